// Round 1
// baseline (4961.563 us; speedup 1.0000x reference)
//
#include <hip/hip_runtime.h>

#define T_TOK 4096
#define HID   4096
#define IMD   11008
#define NADP  4
#define RNK   16

using f32x4  = __attribute__((ext_vector_type(4))) float;
using bf16x8 = __attribute__((ext_vector_type(8))) __bf16;

union FragCast { int4 i; bf16x8 b; };

__device__ __forceinline__ unsigned f2bf_bits(float f) {
  unsigned u = __float_as_uint(f);
  return (u + 0x7fffu + ((u >> 16) & 1u)) >> 16;   // RNE f32 -> bf16
}
__device__ __forceinline__ float bf2f(short s) {
  return __uint_as_float(((unsigned)(unsigned short)s) << 16);
}
__device__ __forceinline__ int4 cvt8(const float4 f0, const float4 f1) {
  int4 r;
  r.x = f2bf_bits(f0.x) | (f2bf_bits(f0.y) << 16);
  r.y = f2bf_bits(f0.z) | (f2bf_bits(f0.w) << 16);
  r.z = f2bf_bits(f1.x) | (f2bf_bits(f1.y) << 16);
  r.w = f2bf_bits(f1.z) | (f2bf_bits(f1.w) << 16);
  return r;
}

// ---------------------------------------------------------------- prep kernels
__global__ void cvt_f32_to_bf16(const float* __restrict__ in,
                                short* __restrict__ out, int n8) {
  for (int c = blockIdx.x * blockDim.x + threadIdx.x; c < n8;
       c += gridDim.x * blockDim.x) {
    const float4* p = (const float4*)(in + (long)c * 8);
    ((int4*)out)[c] = cvt8(p[0], p[1]);
  }
}

// src: [A*R][N] f32 (wb), dst: [N][64] f32 (wb^T), reads coalesced
__global__ void build_wbT(const float* __restrict__ src,
                          float* __restrict__ dst, int N) {
  int i  = blockIdx.x * blockDim.x + threadIdx.x;
  int ar = blockIdx.y;
  if (i < N) dst[(long)i * 64 + ar] = src[(long)ar * N + i];
}

// per-token rank projection: out[t][a*16+r] = mask * sum_h Abf[t][h]*wa[a][h][r]
template <int KD, int NOUT>
__global__ __launch_bounds__(256)
void lora_proj(const short* __restrict__ Abf, const float* __restrict__ wa0,
               const float* __restrict__ wa1, const int* __restrict__ seg,
               short* __restrict__ out0, short* __restrict__ out1) {
  __shared__ __align__(16) short rowbuf[KD];
  __shared__ float part[NOUT][4][16];
  int t = blockIdx.x, tid = threadIdx.x;
  int a = seg[t];
  const int4* src = (const int4*)(Abf + (long)t * KD);
  for (int c = tid; c < KD / 8; c += 256) ((int4*)rowbuf)[c] = src[c];
  __syncthreads();
  int w = tid >> 6, l = tid & 63;
  int r = l & 15, g = l >> 4;
  const int HW = KD / 4;
  float s0 = 0.f, s1 = 0.f;
  const float* p0 = wa0 + (long)a * KD * 16 + r;
  const float* p1 = (NOUT == 2) ? (wa1 + (long)a * KD * 16 + r) : nullptr;
  int h = w * HW + g;
  for (int k = 0; k < HW / 4; ++k, h += 4) {
    float xv = bf2f(rowbuf[h]);
    s0 = fmaf(xv, p0[(long)h * 16], s0);
    if (NOUT == 2) s1 = fmaf(xv, p1[(long)h * 16], s1);
  }
  s0 += __shfl_xor(s0, 16); s0 += __shfl_xor(s0, 32);
  if (NOUT == 2) { s1 += __shfl_xor(s1, 16); s1 += __shfl_xor(s1, 32); }
  if (l < 16) { part[0][w][r] = s0; if (NOUT == 2) part[1][w][r] = s1; }
  __syncthreads();
  if (tid < 64 * NOUT) {
    int m = tid >> 6, ar = tid & 63;
    float v = 0.f;
    if ((ar >> 4) == a) {
      int r2 = ar & 15;
      v = part[m][0][r2] + part[m][1][r2] + part[m][2][r2] + part[m][3][r2];
    }
    short b = (short)f2bf_bits(v);
    short* o = (m == 0) ? out0 : out1;
    o[(long)t * 64 + ar] = b;
  }
}

// -------------------------------------------------------------------- GEMM
// C[M][N] (+= LoRA via augmented K-steps) with A[M][K] bf16, B[N][K] f32.
// NB==2: B0=gate_w,B1=up_w, out = bf16(silu(g)*u).  NB==1: B0=down_w, out f32.
template <int NB>
__global__ __launch_bounds__(512, 2)
void gemm_bf16(const short* __restrict__ A, const short* __restrict__ Ag0,
               const short* __restrict__ Ag1, const float* __restrict__ B0,
               const float* __restrict__ B1, const float* __restrict__ BT0,
               const float* __restrict__ BT1, short* __restrict__ outT,
               float* __restrict__ outF, int M, int N, int K) {
  __shared__ int4 smem[(NB + 1) * 1024];   // 16KB per tile (A, B0[, B1])
  int4* sA  = smem;
  int4* sB0 = smem + 1024;
  int4* sB1 = smem + 2048;

  const int nbx = M >> 7, nby = N >> 7;
  int nwg = nbx * nby;
  int orig = blockIdx.x;
  int q = nwg >> 3, rr = nwg & 7;
  int xcd = orig & 7, loc = orig >> 3;
  int swz = (xcd < rr ? xcd * (q + 1) : rr * (q + 1) + (xcd - rr) * q) + loc;
  int bx = swz % nbx, by = swz / nbx;          // row-block fastest per XCD chunk
  long row0 = (long)bx << 7, col0 = (long)by << 7;

  int tid = threadIdx.x;
  int l = tid & 63, wid = tid >> 6;
  int wr = wid >> 2, wc = wid & 3;
  int lrow = l & 15, lhi = l >> 4;
  int md = lrow & 7;

  int arow8[4], brow8[2];
#pragma unroll
  for (int mi = 0; mi < 4; ++mi) arow8[mi] = (wr * 64 + mi * 16 + lrow) * 8;
#pragma unroll
  for (int ni = 0; ni < 2; ++ni) brow8[ni] = (wc * 32 + ni * 16 + lrow) * 8;

  f32x4 acc0[4][2], acc1[4][2];
  f32x4 zr = {0.f, 0.f, 0.f, 0.f};
#pragma unroll
  for (int mi = 0; mi < 4; ++mi)
#pragma unroll
    for (int ni = 0; ni < 2; ++ni) { acc0[mi][ni] = zr; acc1[mi][ni] = zr; }

  const int K64 = K >> 6;
  const int iters = K64 + NB;

  int r0 = tid >> 3, j0 = tid & 7;
  int ci1 = tid + 512, r1 = ci1 >> 3, j1 = ci1 & 7;
  int wA0 = r0 * 8 + (j0 ^ (r0 & 7));
  int wA1 = r1 * 8 + (j1 ^ (r1 & 7));

  struct St {
    int4 a0, a1;
    float4 g0, g1, g2, g3;
    float4 u0, u1, u2, u3;
    int m0, m1;
  } cur, nxt;

  auto prefetch = [&](int it, St& st) {
    const short* aSrc; int aLd;
    const float* b0Src = nullptr; const float* b1Src = nullptr; int bLd = 0;
    st.m0 = 0; st.m1 = 0;
    if (it < K64) {
      aSrc = A + row0 * K + it * 64; aLd = K;
      b0Src = B0 + col0 * K + it * 64;
      if (NB == 2) b1Src = B1 + col0 * K + it * 64;
      bLd = K; st.m0 = 1; st.m1 = (NB == 2) ? 1 : 0;
    } else if (it == K64) {
      aSrc = Ag0 + row0 * 64; aLd = 64;
      b0Src = BT0 + col0 * 64; bLd = 64; st.m0 = 1;
    } else {
      aSrc = Ag1 + row0 * 64; aLd = 64;
      b1Src = BT1 + col0 * 64; bLd = 64; st.m1 = 1;
    }
    st.a0 = *(const int4*)(aSrc + (long)r0 * aLd + j0 * 8);
    st.a1 = *(const int4*)(aSrc + (long)r1 * aLd + j1 * 8);
    if (st.m0) {
      const float* p = b0Src + (long)r0 * bLd + j0 * 8;
      st.g0 = *(const float4*)p; st.g1 = *(const float4*)(p + 4);
      p = b0Src + (long)r1 * bLd + j1 * 8;
      st.g2 = *(const float4*)p; st.g3 = *(const float4*)(p + 4);
    }
    if constexpr (NB == 2) {
      if (st.m1) {
        const float* p = b1Src + (long)r0 * bLd + j0 * 8;
        st.u0 = *(const float4*)p; st.u1 = *(const float4*)(p + 4);
        p = b1Src + (long)r1 * bLd + j1 * 8;
        st.u2 = *(const float4*)p; st.u3 = *(const float4*)(p + 4);
      }
    }
  };

  prefetch(0, cur);
  for (int it = 0; it < iters; ++it) {
    __syncthreads();                      // prev compute done, LDS free
    sA[wA0] = cur.a0;
    sA[wA1] = cur.a1;
    if (cur.m0) {
      sB0[wA0] = cvt8(cur.g0, cur.g1);
      sB0[wA1] = cvt8(cur.g2, cur.g3);
    }
    if constexpr (NB == 2) {
      if (cur.m1) {
        sB1[wA0] = cvt8(cur.u0, cur.u1);
        sB1[wA1] = cvt8(cur.u2, cur.u3);
      }
    }
    int m0 = cur.m0, m1 = cur.m1;
    __syncthreads();                      // LDS tiles ready
    if (it + 1 < iters) prefetch(it + 1, nxt);  // overlap HBM with MFMA
#pragma unroll
    for (int kk = 0; kk < 2; ++kk) {
      int ck = (kk * 4 + lhi) ^ md;
      bf16x8 aF[4];
#pragma unroll
      for (int mi = 0; mi < 4; ++mi) {
        FragCast fc; fc.i = sA[arow8[mi] + ck]; aF[mi] = fc.b;
      }
      if (m0) {
        bf16x8 bF[2];
#pragma unroll
        for (int ni = 0; ni < 2; ++ni) {
          FragCast fc; fc.i = sB0[brow8[ni] + ck]; bF[ni] = fc.b;
        }
#pragma unroll
        for (int mi = 0; mi < 4; ++mi)
#pragma unroll
          for (int ni = 0; ni < 2; ++ni)
            acc0[mi][ni] = __builtin_amdgcn_mfma_f32_16x16x32_bf16(
                aF[mi], bF[ni], acc0[mi][ni], 0, 0, 0);
      }
      if constexpr (NB == 2) {
        if (m1) {
          bf16x8 bF[2];
#pragma unroll
          for (int ni = 0; ni < 2; ++ni) {
            FragCast fc; fc.i = sB1[brow8[ni] + ck]; bF[ni] = fc.b;
          }
#pragma unroll
          for (int mi = 0; mi < 4; ++mi)
#pragma unroll
            for (int ni = 0; ni < 2; ++ni)
              acc1[mi][ni] = __builtin_amdgcn_mfma_f32_16x16x32_bf16(
                  aF[mi], bF[ni], acc1[mi][ni], 0, 0, 0);
        }
      }
    }
    cur = nxt;
  }

  // epilogue: C/D layout col=lane&15, row=(lane>>4)*4+reg  [m89]
#pragma unroll
  for (int mi = 0; mi < 4; ++mi)
#pragma unroll
    for (int ni = 0; ni < 2; ++ni)
#pragma unroll
      for (int j = 0; j < 4; ++j) {
        long grow = row0 + wr * 64 + mi * 16 + lhi * 4 + j;
        long gcol = col0 + wc * 32 + ni * 16 + lrow;
        if constexpr (NB == 2) {
          float g = acc0[mi][ni][j], u = acc1[mi][ni][j];
          float t = g * (1.f / (1.f + __expf(-g))) * u;   // silu(g)*u
          outT[grow * N + gcol] = (short)f2bf_bits(t);
        } else {
          outF[grow * N + gcol] = acc0[mi][ni][j];
        }
      }
}

// ---------------------------------------------------------------- launcher
extern "C" void kernel_launch(void* const* d_in, const int* in_sizes, int n_in,
                              void* d_out, int out_size, void* d_ws,
                              size_t ws_size, hipStream_t stream) {
  const float* x       = (const float*)d_in[0];
  const float* gate_w  = (const float*)d_in[1];
  const float* up_w    = (const float*)d_in[2];
  const float* down_w  = (const float*)d_in[3];
  const float* gate_wa = (const float*)d_in[4];
  const float* gate_wb = (const float*)d_in[5];
  const float* up_wa   = (const float*)d_in[6];
  const float* up_wb   = (const float*)d_in[7];
  const float* down_wa = (const float*)d_in[8];
  const float* down_wb = (const float*)d_in[9];
  const int*   seg     = (const int*)d_in[10];

  char* ws = (char*)d_ws;
  short* x_bf  = (short*)(ws);                    // [T][H] bf16   33.5 MB
  short* t_act = (short*)(ws + 33554432);         // [T][I] bf16   90.2 MB
  short* xa_g  = (short*)(ws + 123731968);        // [T][64] bf16
  short* xa_u  = (short*)(ws + 124256256);
  short* ta_d  = (short*)(ws + 124780544);
  float* wbT_g = (float*)(ws + 125304832);        // [I][64] f32
  float* wbT_u = (float*)(ws + 128122880);
  float* wbT_d = (float*)(ws + 130940928);        // [H][64] f32

  cvt_f32_to_bf16<<<2048, 256, 0, stream>>>(x, x_bf, T_TOK * HID / 8);
  build_wbT<<<dim3(IMD / 256, 64), 256, 0, stream>>>(gate_wb, wbT_g, IMD);
  build_wbT<<<dim3(IMD / 256, 64), 256, 0, stream>>>(up_wb, wbT_u, IMD);
  build_wbT<<<dim3(HID / 256, 64), 256, 0, stream>>>(down_wb, wbT_d, HID);
  lora_proj<HID, 2><<<T_TOK, 256, 0, stream>>>(x_bf, gate_wa, up_wa, seg,
                                               xa_g, xa_u);
  gemm_bf16<2><<<(T_TOK / 128) * (IMD / 128), 512, 0, stream>>>(
      x_bf, xa_g, xa_u, gate_w, up_w, wbT_g, wbT_u, t_act, nullptr,
      T_TOK, IMD, HID);
  lora_proj<IMD, 1><<<T_TOK, 256, 0, stream>>>(t_act, down_wa, nullptr, seg,
                                               ta_d, nullptr);
  gemm_bf16<1><<<(T_TOK / 128) * (HID / 128), 512, 0, stream>>>(
      t_act, ta_d, nullptr, down_w, nullptr, wbT_d, nullptr, nullptr,
      (float*)d_out, T_TOK, HID, IMD);
}

// Round 2
// 2154.760 us; speedup vs baseline: 2.3026x; 2.3026x over previous
//
#include <hip/hip_runtime.h>

#define T_TOK 4096
#define HID   4096
#define IMD   11008
#define NADP  4
#define RNK   16

using f32x4  = __attribute__((ext_vector_type(4))) float;
using bf16x8 = __attribute__((ext_vector_type(8))) __bf16;

union FragCast { int4 i; bf16x8 b; };

__device__ __forceinline__ unsigned f2bf_bits(float f) {
  unsigned u = __float_as_uint(f);
  return (u + 0x7fffu + ((u >> 16) & 1u)) >> 16;   // RNE f32 -> bf16
}
__device__ __forceinline__ float bf2f(short s) {
  return __uint_as_float(((unsigned)(unsigned short)s) << 16);
}
__device__ __forceinline__ int4 cvt8(const float4 f0, const float4 f1) {
  int4 r;
  r.x = f2bf_bits(f0.x) | (f2bf_bits(f0.y) << 16);
  r.y = f2bf_bits(f0.z) | (f2bf_bits(f0.w) << 16);
  r.z = f2bf_bits(f1.x) | (f2bf_bits(f1.y) << 16);
  r.w = f2bf_bits(f1.z) | (f2bf_bits(f1.w) << 16);
  return r;
}

__device__ __forceinline__ void gload16(const void* g, void* l) {
  __builtin_amdgcn_global_load_lds(
      (__attribute__((address_space(1))) void*)g,
      (__attribute__((address_space(3))) void*)l, 16, 0, 0);
}

// ---------------------------------------------------------------- prep kernels
__global__ void cvt_f32_to_bf16(const float* __restrict__ in,
                                short* __restrict__ out, int n8) {
  for (int c = blockIdx.x * blockDim.x + threadIdx.x; c < n8;
       c += gridDim.x * blockDim.x) {
    const float4* p = (const float4*)(in + (long)c * 8);
    ((int4*)out)[c] = cvt8(p[0], p[1]);
  }
}

// src: [A*R][N] f32 (wb), dst: [N][64] bf16 (wb^T), reads coalesced
__global__ void build_wbT(const float* __restrict__ src,
                          short* __restrict__ dst, int N) {
  int i  = blockIdx.x * blockDim.x + threadIdx.x;
  int ar = blockIdx.y;
  if (i < N) dst[(long)i * 64 + ar] = (short)f2bf_bits(src[(long)ar * N + i]);
}

// per-token rank projection: out[t][a*16+r] = mask * sum_h Abf[t][h]*wa[a][h][r]
template <int KD, int NOUT>
__global__ __launch_bounds__(256)
void lora_proj(const short* __restrict__ Abf, const float* __restrict__ wa0,
               const float* __restrict__ wa1, const int* __restrict__ seg,
               short* __restrict__ out0, short* __restrict__ out1) {
  __shared__ __align__(16) short rowbuf[KD];
  __shared__ float part[NOUT][4][16];
  int t = blockIdx.x, tid = threadIdx.x;
  int a = seg[t];
  const int4* src = (const int4*)(Abf + (long)t * KD);
  for (int c = tid; c < KD / 8; c += 256) ((int4*)rowbuf)[c] = src[c];
  __syncthreads();
  int w = tid >> 6, l = tid & 63;
  int r = l & 15, g = l >> 4;
  const int HW = KD / 4;
  float s0 = 0.f, s1 = 0.f;
  const float* p0 = wa0 + (long)a * KD * 16 + r;
  const float* p1 = (NOUT == 2) ? (wa1 + (long)a * KD * 16 + r) : nullptr;
  int h = w * HW + g;
  for (int k = 0; k < HW / 4; ++k, h += 4) {
    float xv = bf2f(rowbuf[h]);
    s0 = fmaf(xv, p0[(long)h * 16], s0);
    if (NOUT == 2) s1 = fmaf(xv, p1[(long)h * 16], s1);
  }
  s0 += __shfl_xor(s0, 16); s0 += __shfl_xor(s0, 32);
  if (NOUT == 2) { s1 += __shfl_xor(s1, 16); s1 += __shfl_xor(s1, 32); }
  if (l < 16) { part[0][w][r] = s0; if (NOUT == 2) part[1][w][r] = s1; }
  __syncthreads();
  if (tid < 64 * NOUT) {
    int m = tid >> 6, ar = tid & 63;
    float v = 0.f;
    if ((ar >> 4) == a) {
      int r2 = ar & 15;
      v = part[m][0][r2] + part[m][1][r2] + part[m][2][r2] + part[m][3][r2];
    }
    short b = (short)f2bf_bits(v);
    short* o = (m == 0) ? out0 : out1;
    o[(long)t * 64 + ar] = b;
  }
}

// -------------------------------------------------------------- GEMM (m97)
// C[M][N] = A[M][K] @ B[N][K]^T, bf16 inputs, + LoRA augmented K-step.
// MODE 0: store bf16. MODE 1: t = silu(g)*acc, g from gbuf; store bf16 (in
// place over gbuf is allowed). MODE 2: store f32.
// 128x128 tile, BK=64, 256 threads (4 waves 2x2, each 64x64), single-buffer
// LDS, global_load_lds width 16, 2 barriers per K-step.
template <int MODE>
__global__ __launch_bounds__(256)
void gemm_lds(const short* __restrict__ A, const short* __restrict__ B,
              const short* __restrict__ Aaug, const short* __restrict__ Baug,
              const short* __restrict__ gbuf, short* __restrict__ outB,
              float* __restrict__ outF, int M, int N, int K) {
  __shared__ __align__(16) short sA[128 * 64];
  __shared__ __align__(16) short sB[128 * 64];

  const int nbx = M >> 7, nby = N >> 7;
  int nwg = nbx * nby;
  int orig = blockIdx.x;
  int q = nwg >> 3, rr = nwg & 7;
  int xcd = orig & 7, loc = orig >> 3;
  int swz = (xcd < rr ? xcd * (q + 1) : rr * (q + 1) + (xcd - rr) * q) + loc;
  int bx = swz % nbx, by = swz / nbx;   // row-block fastest: weight-tile reuse
  long row0 = (long)bx << 7, col0 = (long)by << 7;

  int tid = threadIdx.x;
  int l = tid & 63, wid = tid >> 6;
  int wr = wid >> 1, wc = wid & 1;      // 2x2 waves, 64x64 each
  int lrow = l & 15, lhi = l >> 4;

  f32x4 acc[4][4];
  f32x4 zr = {0.f, 0.f, 0.f, 0.f};
#pragma unroll
  for (int mi = 0; mi < 4; ++mi)
#pragma unroll
    for (int ni = 0; ni < 4; ++ni) acc[mi][ni] = zr;

  const int K64 = K >> 6;
  for (int it = 0; it <= K64; ++it) {
    const short* aSrc; const short* bSrc; long aLd, bLd;
    if (it < K64) {
      aSrc = A + row0 * K + it * 64; aLd = K;
      bSrc = B + col0 * K + it * 64; bLd = K;
    } else {                                   // LoRA augmented K-step
      aSrc = Aaug + row0 * 64; aLd = 64;
      bSrc = Baug + col0 * 64; bLd = 64;
    }
    __syncthreads();                           // prev tile consumers done
#pragma unroll
    for (int i = 0; i < 4; ++i) {
      int idx = i * 256 + tid;                 // 16B chunk id
      int r = idx >> 3, c8 = idx & 7;
      gload16(aSrc + (long)r * aLd + c8 * 8, (char*)sA + idx * 16);
    }
#pragma unroll
    for (int i = 0; i < 4; ++i) {
      int idx = i * 256 + tid;
      int r = idx >> 3, c8 = idx & 7;
      gload16(bSrc + (long)r * bLd + c8 * 8, (char*)sB + idx * 16);
    }
    __syncthreads();                           // vmcnt(0) drained by compiler
#pragma unroll
    for (int kk = 0; kk < 2; ++kk) {
      int koff = kk * 64 + lhi * 16;           // byte offset within 128B row
      bf16x8 aF[4], bF[4];
#pragma unroll
      for (int mi = 0; mi < 4; ++mi) {
        FragCast fc;
        fc.i = *(const int4*)((const char*)sA +
                              (wr * 64 + mi * 16 + lrow) * 128 + koff);
        aF[mi] = fc.b;
      }
#pragma unroll
      for (int ni = 0; ni < 4; ++ni) {
        FragCast fc;
        fc.i = *(const int4*)((const char*)sB +
                              (wc * 64 + ni * 16 + lrow) * 128 + koff);
        bF[ni] = fc.b;
      }
#pragma unroll
      for (int mi = 0; mi < 4; ++mi)
#pragma unroll
        for (int ni = 0; ni < 4; ++ni)
          acc[mi][ni] = __builtin_amdgcn_mfma_f32_16x16x32_bf16(
              aF[mi], bF[ni], acc[mi][ni], 0, 0, 0);
    }
  }

  // epilogue: C/D layout col=lane&15, row=(lane>>4)*4+reg  [m89]
#pragma unroll
  for (int mi = 0; mi < 4; ++mi)
#pragma unroll
    for (int ni = 0; ni < 4; ++ni)
#pragma unroll
      for (int j = 0; j < 4; ++j) {
        long grow = row0 + wr * 64 + mi * 16 + lhi * 4 + j;
        long gcol = col0 + wc * 64 + ni * 16 + lrow;
        long idx = grow * N + gcol;
        float v = acc[mi][ni][j];
        if constexpr (MODE == 0) {
          outB[idx] = (short)f2bf_bits(v);
        } else if constexpr (MODE == 1) {
          float g = bf2f(gbuf[idx]);
          float t = g * (1.f / (1.f + __expf(-g))) * v;   // silu(g)*u
          outB[idx] = (short)f2bf_bits(t);
        } else {
          outF[idx] = v;
        }
      }
}

// ---------------------------------------------------------------- launcher
extern "C" void kernel_launch(void* const* d_in, const int* in_sizes, int n_in,
                              void* d_out, int out_size, void* d_ws,
                              size_t ws_size, hipStream_t stream) {
  const float* x       = (const float*)d_in[0];
  const float* gate_w  = (const float*)d_in[1];
  const float* up_w    = (const float*)d_in[2];
  const float* down_w  = (const float*)d_in[3];
  const float* gate_wa = (const float*)d_in[4];
  const float* gate_wb = (const float*)d_in[5];
  const float* up_wa   = (const float*)d_in[6];
  const float* up_wb   = (const float*)d_in[7];
  const float* down_wa = (const float*)d_in[8];
  const float* down_wb = (const float*)d_in[9];
  const int*   seg     = (const int*)d_in[10];

  char* ws = (char*)d_ws;
  short* x_bf  = (short*)(ws);                    // [T][H] bf16      33.55 MB
  short* w1_bf = (short*)(ws + 33554432);         // gate_w, later down_w  90.18
  short* w2_bf = (short*)(ws + 123731968);        // up_w bf16        90.18 MB
  short* g_buf = (short*)(ws + 213909504);        // gate out -> t_act 90.18 MB
  short* xa_g  = (short*)(ws + 304087040);        // [T][64] bf16
  short* xa_u  = (short*)(ws + 304611328);
  short* ta_d  = (short*)(ws + 305135616);
  short* wbT_g = (short*)(ws + 305659904);        // [I][64] bf16
  short* wbT_u = (short*)(ws + 307068928);
  short* wbT_d = (short*)(ws + 308477952);        // [H][64] bf16

  // conversions to bf16
  cvt_f32_to_bf16<<<2048, 256, 0, stream>>>(x, x_bf, T_TOK * HID / 8);
  cvt_f32_to_bf16<<<2048, 256, 0, stream>>>(gate_w, w1_bf, IMD * HID / 8);
  cvt_f32_to_bf16<<<2048, 256, 0, stream>>>(up_w, w2_bf, IMD * HID / 8);
  build_wbT<<<dim3(IMD / 256, 64), 256, 0, stream>>>(gate_wb, wbT_g, IMD);
  build_wbT<<<dim3(IMD / 256, 64), 256, 0, stream>>>(up_wb, wbT_u, IMD);
  build_wbT<<<dim3(HID / 256, 64), 256, 0, stream>>>(down_wb, wbT_d, HID);
  lora_proj<HID, 2><<<T_TOK, 256, 0, stream>>>(x_bf, gate_wa, up_wa, seg,
                                               xa_g, xa_u);
  // gate: g_buf = x @ gate_w^T + lora            [M=T, N=I, K=H]
  gemm_lds<0><<<(T_TOK / 128) * (IMD / 128), 256, 0, stream>>>(
      x_bf, w1_bf, xa_g, wbT_g, nullptr, g_buf, nullptr, T_TOK, IMD, HID);
  // up (+silu fuse): g_buf = silu(g_buf) * (x @ up_w^T + lora)
  gemm_lds<1><<<(T_TOK / 128) * (IMD / 128), 256, 0, stream>>>(
      x_bf, w2_bf, xa_u, wbT_u, g_buf, g_buf, nullptr, T_TOK, IMD, HID);
  // reuse w1 region for down_w (gate GEMM has consumed it)
  cvt_f32_to_bf16<<<2048, 256, 0, stream>>>(down_w, w1_bf, HID * IMD / 8);
  lora_proj<IMD, 1><<<T_TOK, 256, 0, stream>>>(g_buf, down_wa, nullptr, seg,
                                               ta_d, nullptr);
  // down: out = t @ down_w^T + lora              [M=T, N=H, K=I]
  gemm_lds<2><<<(T_TOK / 128) * (HID / 128), 256, 0, stream>>>(
      g_buf, w1_bf, ta_d, wbT_d, nullptr, nullptr, (float*)d_out,
      T_TOK, HID, IMD);
}

// Round 3
// 2011.776 us; speedup vs baseline: 2.4663x; 1.0711x over previous
//
#include <hip/hip_runtime.h>

#define T_TOK 4096
#define HID   4096
#define IMD   11008

using f32x4  = __attribute__((ext_vector_type(4))) float;
using bf16x8 = __attribute__((ext_vector_type(8))) __bf16;
union FragCast { int4 i; bf16x8 b; };

__device__ __forceinline__ unsigned f2bf_bits(float f) {
  unsigned u = __float_as_uint(f);
  return (u + 0x7fffu + ((u >> 16) & 1u)) >> 16;   // RNE f32 -> bf16
}
__device__ __forceinline__ float bf2f(short s) {
  return __uint_as_float(((unsigned)(unsigned short)s) << 16);
}
__device__ __forceinline__ int4 cvt8(const float4 f0, const float4 f1) {
  int4 r;
  r.x = f2bf_bits(f0.x) | (f2bf_bits(f0.y) << 16);
  r.y = f2bf_bits(f0.z) | (f2bf_bits(f0.w) << 16);
  r.z = f2bf_bits(f1.x) | (f2bf_bits(f1.y) << 16);
  r.w = f2bf_bits(f1.z) | (f2bf_bits(f1.w) << 16);
  return r;
}
__device__ __forceinline__ void gload16(const void* g, void* l) {
  __builtin_amdgcn_global_load_lds(
      (__attribute__((address_space(1))) void*)g,
      (__attribute__((address_space(3))) void*)l, 16, 0, 0);
}

// ---------------------------------------------------------------- prep kernels
// f32 [R][ldin] row -> bf16 [R][ldout] row (tail cols untouched)
__global__ void cvt_pad(const float* __restrict__ in, short* __restrict__ out,
                        int C8, long ldin, long ldout) {
  long r = blockIdx.x;
  const float4* s = (const float4*)(in + r * ldin);
  int4* d = (int4*)(out + r * ldout);
  for (int c = threadIdx.x; c < C8; c += blockDim.x)
    d[c] = cvt8(s[2 * c], s[2 * c + 1]);
}

// wb f32 [64][N] -> padded tails: out[n][K+ar] = bf16(wb[ar][n])
__global__ void build_wbT_pad(const float* __restrict__ wb,
                              short* __restrict__ out, int N, long ldout,
                              long K) {
  int n = blockIdx.x * blockDim.x + threadIdx.x;
  int ar = blockIdx.y;
  if (n < N) out[(long)n * ldout + K + ar] = (short)f2bf_bits(wb[(long)ar * N + n]);
}

// copy xa [T][64] into padded tail dst[t*ld + j]
__global__ void tail_copy(const short* __restrict__ src, short* dst, long ld) {
  dst[(long)blockIdx.x * ld + threadIdx.x] = src[blockIdx.x * 64 + threadIdx.x];
}

// per-token rank projection: out[t][a*16+r] = mask * sum_h Abf[t][h]*wa[a][h][r]
template <int KD, int NOUT>
__global__ __launch_bounds__(256)
void lora_proj(const short* __restrict__ Abf, long ldA,
               const float* __restrict__ wa0, const float* __restrict__ wa1,
               const int* __restrict__ seg, short* out0, long ld0, short* out1,
               long ld1) {
  __shared__ __align__(16) short rowbuf[KD];
  __shared__ float part[NOUT][4][16];
  int t = blockIdx.x, tid = threadIdx.x;
  int a = seg[t];
  const int4* src = (const int4*)(Abf + (long)t * ldA);
  for (int c = tid; c < KD / 8; c += 256) ((int4*)rowbuf)[c] = src[c];
  __syncthreads();
  int w = tid >> 6, l = tid & 63;
  int r = l & 15, g = l >> 4;
  const int HW = KD / 4;
  float s0 = 0.f, s1 = 0.f;
  const float* p0 = wa0 + (long)a * KD * 16 + r;
  const float* p1 = (NOUT == 2) ? (wa1 + (long)a * KD * 16 + r) : nullptr;
  int h = w * HW + g;
  for (int k = 0; k < HW / 4; ++k, h += 4) {
    float xv = bf2f(rowbuf[h]);
    s0 = fmaf(xv, p0[(long)h * 16], s0);
    if (NOUT == 2) s1 = fmaf(xv, p1[(long)h * 16], s1);
  }
  s0 += __shfl_xor(s0, 16); s0 += __shfl_xor(s0, 32);
  if (NOUT == 2) { s1 += __shfl_xor(s1, 16); s1 += __shfl_xor(s1, 32); }
  if (l < 16) { part[0][w][r] = s0; if (NOUT == 2) part[1][w][r] = s1; }
  __syncthreads();
  if (tid < 64 * NOUT) {
    int m = tid >> 6, ar = tid & 63;
    float v = 0.f;
    if ((ar >> 4) == a) {
      int r2 = ar & 15;
      v = part[m][0][r2] + part[m][1][r2] + part[m][2][r2] + part[m][3][r2];
    }
    short b = (short)f2bf_bits(v);
    if (m == 0) out0[(long)t * ld0 + ar] = b;
    else        out1[(long)t * ld1 + ar] = b;
  }
}

// ------------------------------------------------- GEMM: triple-buffer pipeline
// C[M][N] = A[M][ldK(padded)] @ B[N][ldK]^T over iters K-steps (LoRA folded in
// as the padded tail column block). BM=256, BN=128, BK=64, 512 thr = 8 waves
// (4M x 2N, 64x64 each). 3 LDS buffers of 48KB; stage tile t+2 at iter t into
// the buffer read at iter t-1 (safe: readers done before this iter's barrier);
// per-wave vmcnt(6) BEFORE the barrier proves tile t fully landed for all
// waves. One barrier per K-step; vmcnt(0) only at the last iteration.
// LDS XOR-swizzle applied source-side (rule #21): linear gload_lds dest,
// global chunk (row, c8^(row&7)), read chunk ((kk*4+lhi)^(lrow&7)).
template <int MODE>  // 0: store bf16; 1: silu(gbuf)*acc -> bf16 (in-place ok); 2: f32
__global__ __launch_bounds__(512, 2)
void gemm3(const short* __restrict__ A, const short* __restrict__ B,
           const short* gbuf, short* outB, float* outF, int nby, long ldK,
           int iters, long ldo) {
  extern __shared__ __align__(16) char smem[];
  const int BUFB = 49152;   // 256*64*2 (A) + 128*64*2 (B)

  int nwg = gridDim.x;
  int orig = blockIdx.x;
  int q = nwg >> 3, rr = nwg & 7;
  int xcd = orig & 7, loc = orig >> 3;
  int swz = (xcd < rr ? xcd * (q + 1) : rr * (q + 1) + (xcd - rr) * q) + loc;
  int by = swz % nby, bx = swz / nby;   // col fastest: A panel stays in L2
  long row0 = (long)bx * 256, col0 = (long)by * 128;

  int tid = threadIdx.x;
  int l = tid & 63, wid = tid >> 6;
  int wr = wid >> 1, wc = wid & 1;
  int lrow = l & 15, lhi = l >> 4, md = lrow & 7;

  const short* aP0; const short* aP1; const short* aP2; const short* aP3;
  const short* bP0; const short* bP1;
  int dA0, dA1, dA2, dA3, dB0, dB1;
  {
    int idx, r, c8;
    idx = tid;        r = idx >> 3; c8 = idx & 7;
    aP0 = A + (row0 + r) * ldK + (c8 ^ (r & 7)) * 8; dA0 = idx * 16;
    idx = tid + 512;  r = idx >> 3; c8 = idx & 7;
    aP1 = A + (row0 + r) * ldK + (c8 ^ (r & 7)) * 8; dA1 = idx * 16;
    idx = tid + 1024; r = idx >> 3; c8 = idx & 7;
    aP2 = A + (row0 + r) * ldK + (c8 ^ (r & 7)) * 8; dA2 = idx * 16;
    idx = tid + 1536; r = idx >> 3; c8 = idx & 7;
    aP3 = A + (row0 + r) * ldK + (c8 ^ (r & 7)) * 8; dA3 = idx * 16;
    idx = tid;        r = idx >> 3; c8 = idx & 7;
    bP0 = B + (col0 + r) * ldK + (c8 ^ (r & 7)) * 8; dB0 = 32768 + idx * 16;
    idx = tid + 512;  r = idx >> 3; c8 = idx & 7;
    bP1 = B + (col0 + r) * ldK + (c8 ^ (r & 7)) * 8; dB1 = 32768 + idx * 16;
  }

  auto stage = [&](int bi) {
    char* d = smem + bi * BUFB;
    gload16(aP0, d + dA0); aP0 += 64;
    gload16(aP1, d + dA1); aP1 += 64;
    gload16(aP2, d + dA2); aP2 += 64;
    gload16(aP3, d + dA3); aP3 += 64;
    gload16(bP0, d + dB0); bP0 += 64;
    gload16(bP1, d + dB1); bP1 += 64;
  };

  f32x4 acc[4][4];
  f32x4 zr = {0.f, 0.f, 0.f, 0.f};
#pragma unroll
  for (int mi = 0; mi < 4; ++mi)
#pragma unroll
    for (int ni = 0; ni < 4; ++ni) acc[mi][ni] = zr;

  const int csel0 = (lhi ^ md) * 16;
  const int csel1 = ((4 + lhi) ^ md) * 16;
  const int aBase = (wr * 64 + lrow) * 128;
  const int bBase = 32768 + (wc * 64 + lrow) * 128;

  stage(0);
  stage(1);
  int cb = 0, sb = 2;
  for (int t = 0; t < iters; ++t) {
    if (t + 1 < iters) asm volatile("s_waitcnt vmcnt(6)" ::: "memory");
    else               asm volatile("s_waitcnt vmcnt(0)" ::: "memory");
    asm volatile("s_barrier" ::: "memory");
    if (t + 2 < iters) { stage(sb); sb = (sb == 2) ? 0 : sb + 1; }
    const char* bc = smem + cb * BUFB;
    cb = (cb == 2) ? 0 : cb + 1;

    bf16x8 aF0[4], aF1[4], bF0[4], bF1[4];
#pragma unroll
    for (int mi = 0; mi < 4; ++mi) {
      FragCast f0, f1;
      f0.i = *(const int4*)(bc + aBase + mi * 2048 + csel0);
      f1.i = *(const int4*)(bc + aBase + mi * 2048 + csel1);
      aF0[mi] = f0.b; aF1[mi] = f1.b;
    }
#pragma unroll
    for (int ni = 0; ni < 4; ++ni) {
      FragCast f0, f1;
      f0.i = *(const int4*)(bc + bBase + ni * 2048 + csel0);
      f1.i = *(const int4*)(bc + bBase + ni * 2048 + csel1);
      bF0[ni] = f0.b; bF1[ni] = f1.b;
    }
    __builtin_amdgcn_s_setprio(1);
#pragma unroll
    for (int mi = 0; mi < 4; ++mi)
#pragma unroll
      for (int ni = 0; ni < 4; ++ni) {
        acc[mi][ni] = __builtin_amdgcn_mfma_f32_16x16x32_bf16(
            aF0[mi], bF0[ni], acc[mi][ni], 0, 0, 0);
        acc[mi][ni] = __builtin_amdgcn_mfma_f32_16x16x32_bf16(
            aF1[mi], bF1[ni], acc[mi][ni], 0, 0, 0);
      }
    __builtin_amdgcn_s_setprio(0);
  }

  // epilogue: C/D layout col=lane&15, row=(lane>>4)*4+reg  [m89]
#pragma unroll
  for (int mi = 0; mi < 4; ++mi)
#pragma unroll
    for (int ni = 0; ni < 4; ++ni)
#pragma unroll
      for (int j = 0; j < 4; ++j) {
        long grow = row0 + wr * 64 + mi * 16 + lhi * 4 + j;
        long gcol = col0 + wc * 64 + ni * 16 + lrow;
        long idx = grow * ldo + gcol;
        float v = acc[mi][ni][j];
        if constexpr (MODE == 0) {
          outB[idx] = (short)f2bf_bits(v);
        } else if constexpr (MODE == 1) {
          float g = bf2f(gbuf[idx]);
          float t2 = g * (1.f / (1.f + __expf(-g))) * v;   // silu(g)*u
          outB[idx] = (short)f2bf_bits(t2);
        } else {
          outF[idx] = v;
        }
      }
}

// ---------------------------------------------------------------- launcher
extern "C" void kernel_launch(void* const* d_in, const int* in_sizes, int n_in,
                              void* d_out, int out_size, void* d_ws,
                              size_t ws_size, hipStream_t stream) {
  const float* x       = (const float*)d_in[0];
  const float* gate_w  = (const float*)d_in[1];
  const float* up_w    = (const float*)d_in[2];
  const float* down_w  = (const float*)d_in[3];
  const float* gate_wa = (const float*)d_in[4];
  const float* gate_wb = (const float*)d_in[5];
  const float* up_wa   = (const float*)d_in[6];
  const float* up_wb   = (const float*)d_in[7];
  const float* down_wa = (const float*)d_in[8];
  const float* down_wb = (const float*)d_in[9];
  const int*   seg     = (const int*)d_in[10];

  char* ws = (char*)d_ws;
  short* xg_pad = (short*)(ws);                   // [4096][4160]  34.1 MB
  short* wA     = (short*)(ws + 34078720);        // gate_w pad -> down_w pad
  short* wB     = (short*)(ws + 125665280);       // up_w pad      91.6 MB
  short* t_pad  = (short*)(ws + 217251840);       // [4096][11072] 90.7 MB
  short* xa_u   = (short*)(ws + 307953664);       // [4096][64]

  const int LDS_BYTES = 147456;
  hipFuncSetAttribute(reinterpret_cast<const void*>(&gemm3<0>),
                      hipFuncAttributeMaxDynamicSharedMemorySize, LDS_BYTES);
  hipFuncSetAttribute(reinterpret_cast<const void*>(&gemm3<1>),
                      hipFuncAttributeMaxDynamicSharedMemorySize, LDS_BYTES);
  hipFuncSetAttribute(reinterpret_cast<const void*>(&gemm3<2>),
                      hipFuncAttributeMaxDynamicSharedMemorySize, LDS_BYTES);

  // bf16 padded operand build
  cvt_pad<<<T_TOK, 256, 0, stream>>>(x, xg_pad, 512, HID, 4160);
  cvt_pad<<<IMD, 256, 0, stream>>>(gate_w, wA, 512, HID, 4160);
  cvt_pad<<<IMD, 256, 0, stream>>>(up_w, wB, 512, HID, 4160);
  build_wbT_pad<<<dim3(43, 64), 256, 0, stream>>>(gate_wb, wA, IMD, 4160, HID);
  build_wbT_pad<<<dim3(43, 64), 256, 0, stream>>>(up_wb, wB, IMD, 4160, HID);
  lora_proj<HID, 2><<<T_TOK, 256, 0, stream>>>(
      xg_pad, 4160, gate_wa, up_wa, seg, xg_pad + HID, 4160, xa_u, 64);

  // gate: t_pad = x @ gate_w^T + lora        [M=4096, N=11008, K'=4160]
  gemm3<0><<<1376, 512, LDS_BYTES, stream>>>(xg_pad, wA, nullptr, t_pad,
                                             nullptr, 86, 4160, 65, 11072);
  // swap LoRA tail to up's xa, then up+silu fuse (in place over t_pad)
  tail_copy<<<T_TOK, 64, 0, stream>>>(xa_u, xg_pad + HID, 4160);
  gemm3<1><<<1376, 512, LDS_BYTES, stream>>>(xg_pad, wB, t_pad, t_pad,
                                             nullptr, 86, 4160, 65, 11072);

  // down operand build (wA region is free after gate GEMM)
  cvt_pad<<<T_TOK, 256, 0, stream>>>(down_w, wA, 1376, IMD, 11072);
  build_wbT_pad<<<dim3(16, 64), 256, 0, stream>>>(down_wb, wA, HID, 11072, IMD);
  lora_proj<IMD, 1><<<T_TOK, 256, 0, stream>>>(
      t_pad, 11072, down_wa, nullptr, seg, t_pad + IMD, 11072, nullptr, 64);

  // down: out = t @ down_w^T + lora          [M=4096, N=4096, K'=11072]
  gemm3<2><<<512, 512, LDS_BYTES, stream>>>(t_pad, wA, nullptr, nullptr,
                                            (float*)d_out, 32, 11072, 173,
                                            4096);
}

// Round 4
// 1718.741 us; speedup vs baseline: 2.8867x; 1.1705x over previous
//
#include <hip/hip_runtime.h>

#define T_TOK 4096
#define HID   4096
#define IMD   11008

using f32x4  = __attribute__((ext_vector_type(4))) float;
using bf16x8 = __attribute__((ext_vector_type(8))) __bf16;
union FragCast { int4 i; bf16x8 b; };

__device__ __forceinline__ unsigned f2bf_bits(float f) {
  unsigned u = __float_as_uint(f);
  return (u + 0x7fffu + ((u >> 16) & 1u)) >> 16;   // RNE f32 -> bf16
}
__device__ __forceinline__ float bf2f(short s) {
  return __uint_as_float(((unsigned)(unsigned short)s) << 16);
}
__device__ __forceinline__ int4 cvt8(const float4 f0, const float4 f1) {
  int4 r;
  r.x = f2bf_bits(f0.x) | (f2bf_bits(f0.y) << 16);
  r.y = f2bf_bits(f0.z) | (f2bf_bits(f0.w) << 16);
  r.z = f2bf_bits(f1.x) | (f2bf_bits(f1.y) << 16);
  r.w = f2bf_bits(f1.z) | (f2bf_bits(f1.w) << 16);
  return r;
}
__device__ __forceinline__ void gload16(const void* g, void* l) {
  __builtin_amdgcn_global_load_lds(
      (__attribute__((address_space(1))) void*)g,
      (__attribute__((address_space(3))) void*)l, 16, 0, 0);
}

// ---------------------------------------------------------------- prep kernels
__global__ void cvt_pad(const float* __restrict__ in, short* __restrict__ out,
                        int C8, long ldin, long ldout) {
  long r = blockIdx.x;
  const float4* s = (const float4*)(in + r * ldin);
  int4* d = (int4*)(out + r * ldout);
  for (int c = threadIdx.x; c < C8; c += blockDim.x)
    d[c] = cvt8(s[2 * c], s[2 * c + 1]);
}

__global__ void build_wbT_pad(const float* __restrict__ wb,
                              short* __restrict__ out, int N, long ldout,
                              long K) {
  int n = blockIdx.x * blockDim.x + threadIdx.x;
  int ar = blockIdx.y;
  if (n < N) out[(long)n * ldout + K + ar] = (short)f2bf_bits(wb[(long)ar * N + n]);
}

__global__ void tail_copy(const short* __restrict__ src, short* dst, long ld) {
  dst[(long)blockIdx.x * ld + threadIdx.x] = src[blockIdx.x * 64 + threadIdx.x];
}

// per-token rank projection: out[t][a*16+r] = mask * sum_h Abf[t][h]*wa[a][h][r]
template <int KD, int NOUT>
__global__ __launch_bounds__(256)
void lora_proj(const short* __restrict__ Abf, long ldA,
               const float* __restrict__ wa0, const float* __restrict__ wa1,
               const int* __restrict__ seg, short* out0, long ld0, short* out1,
               long ld1) {
  __shared__ __align__(16) short rowbuf[KD];
  __shared__ float part[NOUT][4][16];
  int t = blockIdx.x, tid = threadIdx.x;
  int a = seg[t];
  const int4* src = (const int4*)(Abf + (long)t * ldA);
  for (int c = tid; c < KD / 8; c += 256) ((int4*)rowbuf)[c] = src[c];
  __syncthreads();
  int w = tid >> 6, l = tid & 63;
  int r = l & 15, g = l >> 4;
  const int HW = KD / 4;
  float s0 = 0.f, s1 = 0.f;
  const float* p0 = wa0 + (long)a * KD * 16 + r;
  const float* p1 = (NOUT == 2) ? (wa1 + (long)a * KD * 16 + r) : nullptr;
  int h = w * HW + g;
  for (int k = 0; k < HW / 4; ++k, h += 4) {
    float xv = bf2f(rowbuf[h]);
    s0 = fmaf(xv, p0[(long)h * 16], s0);
    if (NOUT == 2) s1 = fmaf(xv, p1[(long)h * 16], s1);
  }
  s0 += __shfl_xor(s0, 16); s0 += __shfl_xor(s0, 32);
  if (NOUT == 2) { s1 += __shfl_xor(s1, 16); s1 += __shfl_xor(s1, 32); }
  if (l < 16) { part[0][w][r] = s0; if (NOUT == 2) part[1][w][r] = s1; }
  __syncthreads();
  if (tid < 64 * NOUT) {
    int m = tid >> 6, ar = tid & 63;
    float v = 0.f;
    if ((ar >> 4) == a) {
      int r2 = ar & 15;
      v = part[m][0][r2] + part[m][1][r2] + part[m][2][r2] + part[m][3][r2];
    }
    short b = (short)f2bf_bits(v);
    if (m == 0) out0[(long)t * ld0 + ar] = b;
    else        out1[(long)t * ld1 + ar] = b;
  }
}

// ----------------------------------------------- GEMM: 256x256, A3/B2 pipeline
// C[M][N] = A[M][ldK]@B[N][ldK]^T (LoRA folded as padded K-tail). BM=BN=256,
// BK=64, 512 thr = 8 waves (2M x 4N), per-wave 128x64 output (43.7 FLOP per
// LDS byte). A triple-buffered, B double-buffered (160KB LDS total).
// Schedule per iter t: wait vmcnt(4) [B(t) landed, A(t+1) in flight]; barrier;
// stage B(t+1), A(t+2); compute buf(t). Loads never drain mid-loop (T4).
// WAR safe: staged buffer's previous readers finished before this barrier.
// LDS XOR-swizzle source-side (rule #21): linear dest, global chunk
// c8^(row&7), read chunk ((ks*4+lhi)^(lrow&7)). Zero bank conflicts (R2).
template <int MODE>  // 0: bf16 store; 1: silu(gbuf)*acc -> bf16 in-place; 2: f32
__global__ __launch_bounds__(512, 2)
void gemm256(const short* __restrict__ A, const short* __restrict__ B,
             const short* gbuf, short* outB, float* outF, int nby, long ldK,
             int iters, long ldo) {
  extern __shared__ __align__(16) char smem[];
  // A bufs: 3 x 32KB at 0; B bufs: 2 x 32KB at 98304.

  int nwg = gridDim.x;
  int orig = blockIdx.x;
  int q = nwg >> 3, rr = nwg & 7;
  int xcd = orig & 7, loc = orig >> 3;
  int swz = (xcd < rr ? xcd * (q + 1) : rr * (q + 1) + (xcd - rr) * q) + loc;
  int by = swz % nby, bx = swz / nby;   // col fastest: A panel stays in L2
  long row0 = (long)bx * 256, col0 = (long)by * 256;

  int tid = threadIdx.x;
  int l = tid & 63, wid = tid >> 6;
  int wr = wid >> 2, wc = wid & 3;      // 2M x 4N waves, 128x64 each
  int lrow = l & 15, lhi = l >> 4, md = lrow & 7;

  const short* aP[4]; const short* bP[4];
  int dst[4];
#pragma unroll
  for (int k = 0; k < 4; ++k) {
    int idx = tid + k * 512;
    int r = idx >> 3, c8 = idx & 7;
    aP[k] = A + (row0 + r) * ldK + (c8 ^ (r & 7)) * 8;
    bP[k] = B + (col0 + r) * ldK + (c8 ^ (r & 7)) * 8;
    dst[k] = idx * 16;
  }

  auto stageA = [&](int bi) {
    char* d = smem + bi * 32768;
#pragma unroll
    for (int k = 0; k < 4; ++k) { gload16(aP[k], d + dst[k]); aP[k] += 64; }
  };
  auto stageB = [&](int bi) {
    char* d = smem + 98304 + bi * 32768;
#pragma unroll
    for (int k = 0; k < 4; ++k) { gload16(bP[k], d + dst[k]); bP[k] += 64; }
  };

  f32x4 acc[8][4];
  f32x4 zr = {0.f, 0.f, 0.f, 0.f};
#pragma unroll
  for (int mi = 0; mi < 8; ++mi)
#pragma unroll
    for (int ni = 0; ni < 4; ++ni) acc[mi][ni] = zr;

  const int csel0 = (lhi ^ md) * 16;
  const int csel1 = ((4 + lhi) ^ md) * 16;

  stageA(0); stageB(0); stageA(1);   // queue: [A0, B0, A1]
  int ca = 0, sa = 2;                // A read / stage buffer counters
  for (int t = 0; t < iters; ++t) {
    if (t + 1 < iters) asm volatile("s_waitcnt vmcnt(4)" ::: "memory");
    else               asm volatile("s_waitcnt vmcnt(0)" ::: "memory");
    asm volatile("s_barrier" ::: "memory");
    if (t + 1 < iters) stageB((t + 1) & 1);
    if (t + 2 < iters) { stageA(sa); sa = (sa == 2) ? 0 : sa + 1; }

    const char* Ab = smem + ca * 32768;
    const char* Bb = smem + 98304 + (t & 1) * 32768;
    ca = (ca == 2) ? 0 : ca + 1;

    bf16x8 bF[4][2];
#pragma unroll
    for (int ni = 0; ni < 4; ++ni) {
      const char* base = Bb + (wc * 64 + ni * 16 + lrow) * 128;
      FragCast f0, f1;
      f0.i = *(const int4*)(base + csel0);
      f1.i = *(const int4*)(base + csel1);
      bF[ni][0] = f0.b; bF[ni][1] = f1.b;
    }
#pragma unroll
    for (int qm = 0; qm < 2; ++qm) {
      bf16x8 aF[4][2];
#pragma unroll
      for (int mi = 0; mi < 4; ++mi) {
        const char* base = Ab + (wr * 128 + qm * 64 + mi * 16 + lrow) * 128;
        FragCast f0, f1;
        f0.i = *(const int4*)(base + csel0);
        f1.i = *(const int4*)(base + csel1);
        aF[mi][0] = f0.b; aF[mi][1] = f1.b;
      }
      __builtin_amdgcn_s_setprio(1);
#pragma unroll
      for (int mi = 0; mi < 4; ++mi)
#pragma unroll
        for (int ni = 0; ni < 4; ++ni) {
          acc[qm * 4 + mi][ni] = __builtin_amdgcn_mfma_f32_16x16x32_bf16(
              aF[mi][0], bF[ni][0], acc[qm * 4 + mi][ni], 0, 0, 0);
          acc[qm * 4 + mi][ni] = __builtin_amdgcn_mfma_f32_16x16x32_bf16(
              aF[mi][1], bF[ni][1], acc[qm * 4 + mi][ni], 0, 0, 0);
        }
      __builtin_amdgcn_s_setprio(0);
    }
  }

  // epilogue: C/D layout col=lane&15, row=(lane>>4)*4+reg  [m89]
#pragma unroll
  for (int qm = 0; qm < 2; ++qm)
#pragma unroll
    for (int mi = 0; mi < 4; ++mi)
#pragma unroll
      for (int ni = 0; ni < 4; ++ni)
#pragma unroll
        for (int j = 0; j < 4; ++j) {
          long grow = row0 + wr * 128 + qm * 64 + mi * 16 + lhi * 4 + j;
          long gcol = col0 + wc * 64 + ni * 16 + lrow;
          long idx = grow * ldo + gcol;
          float v = acc[qm * 4 + mi][ni][j];
          if constexpr (MODE == 0) {
            outB[idx] = (short)f2bf_bits(v);
          } else if constexpr (MODE == 1) {
            float g = bf2f(gbuf[idx]);
            float t2 = g * (1.f / (1.f + __expf(-g))) * v;   // silu(g)*u
            outB[idx] = (short)f2bf_bits(t2);
          } else {
            outF[idx] = v;
          }
        }
}

// ---------------------------------------------------------------- launcher
extern "C" void kernel_launch(void* const* d_in, const int* in_sizes, int n_in,
                              void* d_out, int out_size, void* d_ws,
                              size_t ws_size, hipStream_t stream) {
  const float* x       = (const float*)d_in[0];
  const float* gate_w  = (const float*)d_in[1];
  const float* up_w    = (const float*)d_in[2];
  const float* down_w  = (const float*)d_in[3];
  const float* gate_wa = (const float*)d_in[4];
  const float* gate_wb = (const float*)d_in[5];
  const float* up_wa   = (const float*)d_in[6];
  const float* up_wb   = (const float*)d_in[7];
  const float* down_wa = (const float*)d_in[8];
  const float* down_wb = (const float*)d_in[9];
  const int*   seg     = (const int*)d_in[10];

  char* ws = (char*)d_ws;
  short* xg_pad = (short*)(ws);                   // [4096][4160]  34.1 MB
  short* wA     = (short*)(ws + 34078720);        // gate_w pad -> down_w pad
  short* wB     = (short*)(ws + 125665280);       // up_w pad      91.6 MB
  short* t_pad  = (short*)(ws + 217251840);       // [4096][11072] 90.7 MB
  short* xa_u   = (short*)(ws + 307953664);       // [4096][64]

  const int LDS_BYTES = 163840;   // 3 x 32KB A + 2 x 32KB B
  hipFuncSetAttribute(reinterpret_cast<const void*>(&gemm256<0>),
                      hipFuncAttributeMaxDynamicSharedMemorySize, LDS_BYTES);
  hipFuncSetAttribute(reinterpret_cast<const void*>(&gemm256<1>),
                      hipFuncAttributeMaxDynamicSharedMemorySize, LDS_BYTES);
  hipFuncSetAttribute(reinterpret_cast<const void*>(&gemm256<2>),
                      hipFuncAttributeMaxDynamicSharedMemorySize, LDS_BYTES);

  // bf16 padded operand build
  cvt_pad<<<T_TOK, 256, 0, stream>>>(x, xg_pad, 512, HID, 4160);
  cvt_pad<<<IMD, 256, 0, stream>>>(gate_w, wA, 512, HID, 4160);
  cvt_pad<<<IMD, 256, 0, stream>>>(up_w, wB, 512, HID, 4160);
  build_wbT_pad<<<dim3(43, 64), 256, 0, stream>>>(gate_wb, wA, IMD, 4160, HID);
  build_wbT_pad<<<dim3(43, 64), 256, 0, stream>>>(up_wb, wB, IMD, 4160, HID);
  lora_proj<HID, 2><<<T_TOK, 256, 0, stream>>>(
      xg_pad, 4160, gate_wa, up_wa, seg, xg_pad + HID, 4160, xa_u, 64);

  // gate: t_pad = x @ gate_w^T + lora        [M=4096, N=11008, K'=4160]
  gemm256<0><<<16 * 43, 512, LDS_BYTES, stream>>>(
      xg_pad, wA, nullptr, t_pad, nullptr, 43, 4160, 65, 11072);
  // swap LoRA tail to up's xa, then up+silu fuse (in place over t_pad)
  tail_copy<<<T_TOK, 64, 0, stream>>>(xa_u, xg_pad + HID, 4160);
  gemm256<1><<<16 * 43, 512, LDS_BYTES, stream>>>(
      xg_pad, wB, t_pad, t_pad, nullptr, 43, 4160, 65, 11072);

  // down operand build (wA region is free after gate GEMM)
  cvt_pad<<<T_TOK, 256, 0, stream>>>(down_w, wA, 1376, IMD, 11072);
  build_wbT_pad<<<dim3(16, 64), 256, 0, stream>>>(down_wb, wA, HID, 11072, IMD);
  lora_proj<IMD, 1><<<T_TOK, 256, 0, stream>>>(
      t_pad, 11072, down_wa, nullptr, seg, t_pad + IMD, 11072, nullptr, 64);

  // down: out = t @ down_w^T + lora          [M=4096, N=4096, K'=11072]
  gemm256<2><<<16 * 16, 512, LDS_BYTES, stream>>>(
      t_pad, wA, nullptr, nullptr, (float*)d_out, 16, 11072, 173, 4096);
}

// Round 5
// 1679.017 us; speedup vs baseline: 2.9550x; 1.0237x over previous
//
#include <hip/hip_runtime.h>

#define T_TOK 4096
#define HID   4096
#define IMD   11008

using f32x4  = __attribute__((ext_vector_type(4))) float;
using bf16x8 = __attribute__((ext_vector_type(8))) __bf16;
union FragCast { int4 i; bf16x8 b; };

__device__ __forceinline__ unsigned f2bf_bits(float f) {
  unsigned u = __float_as_uint(f);
  return (u + 0x7fffu + ((u >> 16) & 1u)) >> 16;   // RNE f32 -> bf16
}
__device__ __forceinline__ float bf2f(short s) {
  return __uint_as_float(((unsigned)(unsigned short)s) << 16);
}
__device__ __forceinline__ int4 cvt8(const float4 f0, const float4 f1) {
  int4 r;
  r.x = f2bf_bits(f0.x) | (f2bf_bits(f0.y) << 16);
  r.y = f2bf_bits(f0.z) | (f2bf_bits(f0.w) << 16);
  r.z = f2bf_bits(f1.x) | (f2bf_bits(f1.y) << 16);
  r.w = f2bf_bits(f1.z) | (f2bf_bits(f1.w) << 16);
  return r;
}
__device__ __forceinline__ void gload16(const void* g, void* l) {
  __builtin_amdgcn_global_load_lds(
      (__attribute__((address_space(1))) void*)g,
      (__attribute__((address_space(3))) void*)l, 16, 0, 0);
}

// ---------------------------------------------------------------- prep kernels
__global__ void cvt_pad(const float* __restrict__ in, short* __restrict__ out,
                        int C8, long ldin, long ldout) {
  long r = blockIdx.x;
  const float4* s = (const float4*)(in + r * ldin);
  int4* d = (int4*)(out + r * ldout);
  for (int c = threadIdx.x; c < C8; c += blockDim.x)
    d[c] = cvt8(s[2 * c], s[2 * c + 1]);
}

__global__ void build_wbT_pad(const float* __restrict__ wb,
                              short* __restrict__ out, int N, long ldout,
                              long K) {
  int n = blockIdx.x * blockDim.x + threadIdx.x;
  int ar = blockIdx.y;
  if (n < N) out[(long)n * ldout + K + ar] = (short)f2bf_bits(wb[(long)ar * N + n]);
}

__global__ void tail_copy(const short* __restrict__ src, short* dst, long ld) {
  dst[(long)blockIdx.x * ld + threadIdx.x] = src[blockIdx.x * 64 + threadIdx.x];
}

// per-token rank projection: out[t][a*16+r] = mask * sum_h Abf[t][h]*wa[a][h][r]
template <int KD, int NOUT>
__global__ __launch_bounds__(256)
void lora_proj(const short* __restrict__ Abf, long ldA,
               const float* __restrict__ wa0, const float* __restrict__ wa1,
               const int* __restrict__ seg, short* out0, long ld0, short* out1,
               long ld1) {
  __shared__ __align__(16) short rowbuf[KD];
  __shared__ float part[NOUT][4][16];
  int t = blockIdx.x, tid = threadIdx.x;
  int a = seg[t];
  const int4* src = (const int4*)(Abf + (long)t * ldA);
  for (int c = tid; c < KD / 8; c += 256) ((int4*)rowbuf)[c] = src[c];
  __syncthreads();
  int w = tid >> 6, l = tid & 63;
  int r = l & 15, g = l >> 4;
  const int HW = KD / 4;
  float s0 = 0.f, s1 = 0.f;
  const float* p0 = wa0 + (long)a * KD * 16 + r;
  const float* p1 = (NOUT == 2) ? (wa1 + (long)a * KD * 16 + r) : nullptr;
  int h = w * HW + g;
  for (int k = 0; k < HW / 4; ++k, h += 4) {
    float xv = bf2f(rowbuf[h]);
    s0 = fmaf(xv, p0[(long)h * 16], s0);
    if (NOUT == 2) s1 = fmaf(xv, p1[(long)h * 16], s1);
  }
  s0 += __shfl_xor(s0, 16); s0 += __shfl_xor(s0, 32);
  if (NOUT == 2) { s1 += __shfl_xor(s1, 16); s1 += __shfl_xor(s1, 32); }
  if (l < 16) { part[0][w][r] = s0; if (NOUT == 2) part[1][w][r] = s1; }
  __syncthreads();
  if (tid < 64 * NOUT) {
    int m = tid >> 6, ar = tid & 63;
    float v = 0.f;
    if ((ar >> 4) == a) {
      int r2 = ar & 15;
      v = part[m][0][r2] + part[m][1][r2] + part[m][2][r2] + part[m][3][r2];
    }
    short b = (short)f2bf_bits(v);
    if (m == 0) out0[(long)t * ld0 + ar] = b;
    else        out1[(long)t * ld1 + ar] = b;
  }
}

// ------------------------------------- GEMM: 256x256, 4-phase/K-step pipeline
// C[M][N] = A[M][ldK]@B[N][ldK]^T (LoRA folded as padded K-tail). BM=BN=256,
// BK=64, 512 thr = 8 waves (2M x 4N), per-wave 128x64. A triple-buffered,
// B double-buffered (160KB LDS). Each K-step = 4 phases; phase p:
//   {ds_read aF(mi-pair p) [+ bF x8 at p0]  -> stage 1 half-tile (2 gloads)
//    -> [p3: counted vmcnt(4), never 0 mid-loop] -> barrier
//    -> setprio(1) 16 MFMA setprio(0) -> barrier}
// Stage order per step t: p0/p1 = B(t+1) halves, p2/p3 = A(t+2) halves.
// Wait math (per wave, steady): queue at p3 = [A(t+1)x4 | B(t+1)x4 | A(t+2)x4];
// vmcnt(4) confirms A(t+1),B(t+1) for the next step, keeps A(t+2) in flight.
// WAR: B(t+1) overwrites B(t-1)'s buffer (reads ended at step t-1's last
// barrier); A(t+2) overwrites A(t-1)'s. LDS XOR-swizzle source-side (rule
// #21): linear gload dest, global chunk c8^(row&7), read chunk (x^(lrow&7)).
template <int MODE>  // 0: bf16 store; 1: silu(gbuf)*acc -> bf16 in-place; 2: f32
__global__ __launch_bounds__(512, 2)
void gemm256(const short* __restrict__ A, const short* __restrict__ B,
             const short* gbuf, short* outB, float* outF, int nby, long ldK,
             int iters, long ldo) {
  extern __shared__ __align__(16) char smem[];
  // A bufs: 3 x 32KB at 0; B bufs: 2 x 32KB at 98304.

  int nwg = gridDim.x;
  int orig = blockIdx.x;
  int q = nwg >> 3, rr = nwg & 7;
  int xcd = orig & 7, loc = orig >> 3;
  int swz = (xcd < rr ? xcd * (q + 1) : rr * (q + 1) + (xcd - rr) * q) + loc;
  int by = swz % nby, bx = swz / nby;   // col fastest: A panel stays in L2
  long row0 = (long)bx * 256, col0 = (long)by * 256;

  int tid = threadIdx.x;
  int l = tid & 63, wid = tid >> 6;
  int wr = wid >> 2, wc = wid & 3;      // 2M x 4N waves, 128x64 each
  int lrow = l & 15, lhi = l >> 4, md = lrow & 7;

  const short* aP[4]; const short* bP[4];
  int dst[4];
#pragma unroll
  for (int k = 0; k < 4; ++k) {
    int idx = tid + k * 512;
    int r = idx >> 3, c8 = idx & 7;
    aP[k] = A + (row0 + r) * ldK + (c8 ^ (r & 7)) * 8;
    bP[k] = B + (col0 + r) * ldK + (c8 ^ (r & 7)) * 8;
    dst[k] = idx * 16;
  }

  // stage one half-tile (h=0: rows 0-127, h=1: rows 128-255) = 2 gloads
  auto stageA_h = [&](int bi, int h) {
    char* d = smem + bi * 32768;
    gload16(aP[2 * h], d + dst[2 * h]);         aP[2 * h] += 64;
    gload16(aP[2 * h + 1], d + dst[2 * h + 1]); aP[2 * h + 1] += 64;
  };
  auto stageB_h = [&](int bi, int h) {
    char* d = smem + 98304 + bi * 32768;
    gload16(bP[2 * h], d + dst[2 * h]);         bP[2 * h] += 64;
    gload16(bP[2 * h + 1], d + dst[2 * h + 1]); bP[2 * h + 1] += 64;
  };

  f32x4 acc[8][4];
  f32x4 zr = {0.f, 0.f, 0.f, 0.f};
#pragma unroll
  for (int mi = 0; mi < 8; ++mi)
#pragma unroll
    for (int ni = 0; ni < 4; ++ni) acc[mi][ni] = zr;

  const int csel0 = (lhi ^ md) * 16;
  const int csel1 = ((4 + lhi) ^ md) * 16;

  // prologue: A(0), B(0), A(1); confirm A(0),B(0); keep A(1) in flight
  stageA_h(0, 0); stageA_h(0, 1);
  stageB_h(0, 0); stageB_h(0, 1);
  stageA_h(1, 0); stageA_h(1, 1);
  asm volatile("s_waitcnt vmcnt(4)" ::: "memory");
  asm volatile("s_barrier" ::: "memory");

  int ca = 0;                             // A buffer holding A(t)
  for (int t = 0; t < iters; ++t) {
    const char* Ab = smem + ca * 32768;
    const char* Bb = smem + 98304 + (t & 1) * 32768;
    int na2 = (ca >= 1) ? ca - 1 : 2;     // (ca+2)%3 : buffer for A(t+2)
    int nb1 = (t + 1) & 1;
    bf16x8 bF[4][2];

#pragma unroll
    for (int p = 0; p < 4; ++p) {
      // --- ds_read register subtile for this phase
      if (p == 0) {
#pragma unroll
        for (int ni = 0; ni < 4; ++ni) {
          const char* base = Bb + (wc * 64 + ni * 16 + lrow) * 128;
          FragCast f0, f1;
          f0.i = *(const int4*)(base + csel0);
          f1.i = *(const int4*)(base + csel1);
          bF[ni][0] = f0.b; bF[ni][1] = f1.b;
        }
      }
      bf16x8 aF[2][2];
#pragma unroll
      for (int m2 = 0; m2 < 2; ++m2) {
        const char* base = Ab + (wr * 128 + p * 32 + m2 * 16 + lrow) * 128;
        FragCast f0, f1;
        f0.i = *(const int4*)(base + csel0);
        f1.i = *(const int4*)(base + csel1);
        aF[m2][0] = f0.b; aF[m2][1] = f1.b;
      }
      // --- stage one half-tile
      if (p == 0 && t + 1 < iters) stageB_h(nb1, 0);
      if (p == 1 && t + 1 < iters) stageB_h(nb1, 1);
      if (p == 2 && t + 2 < iters) stageA_h(na2, 0);
      if (p == 3) {
        if (t + 2 < iters) {
          stageA_h(na2, 1);
          asm volatile("s_waitcnt vmcnt(4)" ::: "memory");
        } else {
          asm volatile("s_waitcnt vmcnt(0)" ::: "memory");
        }
      }
      asm volatile("s_barrier" ::: "memory");
      // --- MFMA cluster (k-outer: 8 independent accs between reuse)
      __builtin_amdgcn_s_setprio(1);
#pragma unroll
      for (int k = 0; k < 2; ++k)
#pragma unroll
        for (int m2 = 0; m2 < 2; ++m2)
#pragma unroll
          for (int ni = 0; ni < 4; ++ni)
            acc[p * 2 + m2][ni] = __builtin_amdgcn_mfma_f32_16x16x32_bf16(
                aF[m2][k], bF[ni][k], acc[p * 2 + m2][ni], 0, 0, 0);
      __builtin_amdgcn_s_setprio(0);
      asm volatile("s_barrier" ::: "memory");
    }
    ca = (ca == 2) ? 0 : ca + 1;
  }

  // epilogue: C/D layout col=lane&15, row=(lane>>4)*4+reg  [m89]
#pragma unroll
  for (int mi = 0; mi < 8; ++mi)
#pragma unroll
    for (int ni = 0; ni < 4; ++ni)
#pragma unroll
      for (int j = 0; j < 4; ++j) {
        long grow = row0 + wr * 128 + mi * 16 + lhi * 4 + j;
        long gcol = col0 + wc * 64 + ni * 16 + lrow;
        long idx = grow * ldo + gcol;
        float v = acc[mi][ni][j];
        if constexpr (MODE == 0) {
          outB[idx] = (short)f2bf_bits(v);
        } else if constexpr (MODE == 1) {
          float g = bf2f(gbuf[idx]);
          float t2 = g * (1.f / (1.f + __expf(-g))) * v;   // silu(g)*u
          outB[idx] = (short)f2bf_bits(t2);
        } else {
          outF[idx] = v;
        }
      }
}

// ---------------------------------------------------------------- launcher
extern "C" void kernel_launch(void* const* d_in, const int* in_sizes, int n_in,
                              void* d_out, int out_size, void* d_ws,
                              size_t ws_size, hipStream_t stream) {
  const float* x       = (const float*)d_in[0];
  const float* gate_w  = (const float*)d_in[1];
  const float* up_w    = (const float*)d_in[2];
  const float* down_w  = (const float*)d_in[3];
  const float* gate_wa = (const float*)d_in[4];
  const float* gate_wb = (const float*)d_in[5];
  const float* up_wa   = (const float*)d_in[6];
  const float* up_wb   = (const float*)d_in[7];
  const float* down_wa = (const float*)d_in[8];
  const float* down_wb = (const float*)d_in[9];
  const int*   seg     = (const int*)d_in[10];

  char* ws = (char*)d_ws;
  short* xg_pad = (short*)(ws);                   // [4096][4160]  34.1 MB
  short* wA     = (short*)(ws + 34078720);        // gate_w pad -> down_w pad
  short* wB     = (short*)(ws + 125665280);       // up_w pad      91.6 MB
  short* t_pad  = (short*)(ws + 217251840);       // [4096][11072] 90.7 MB
  short* xa_u   = (short*)(ws + 307953664);       // [4096][64]

  const int LDS_BYTES = 163840;   // 3 x 32KB A + 2 x 32KB B
  hipFuncSetAttribute(reinterpret_cast<const void*>(&gemm256<0>),
                      hipFuncAttributeMaxDynamicSharedMemorySize, LDS_BYTES);
  hipFuncSetAttribute(reinterpret_cast<const void*>(&gemm256<1>),
                      hipFuncAttributeMaxDynamicSharedMemorySize, LDS_BYTES);
  hipFuncSetAttribute(reinterpret_cast<const void*>(&gemm256<2>),
                      hipFuncAttributeMaxDynamicSharedMemorySize, LDS_BYTES);

  // bf16 padded operand build
  cvt_pad<<<T_TOK, 256, 0, stream>>>(x, xg_pad, 512, HID, 4160);
  cvt_pad<<<IMD, 256, 0, stream>>>(gate_w, wA, 512, HID, 4160);
  cvt_pad<<<IMD, 256, 0, stream>>>(up_w, wB, 512, HID, 4160);
  build_wbT_pad<<<dim3(43, 64), 256, 0, stream>>>(gate_wb, wA, IMD, 4160, HID);
  build_wbT_pad<<<dim3(43, 64), 256, 0, stream>>>(up_wb, wB, IMD, 4160, HID);
  lora_proj<HID, 2><<<T_TOK, 256, 0, stream>>>(
      xg_pad, 4160, gate_wa, up_wa, seg, xg_pad + HID, 4160, xa_u, 64);

  // gate: t_pad = x @ gate_w^T + lora        [M=4096, N=11008, K'=4160]
  gemm256<0><<<16 * 43, 512, LDS_BYTES, stream>>>(
      xg_pad, wA, nullptr, t_pad, nullptr, 43, 4160, 65, 11072);
  // swap LoRA tail to up's xa, then up+silu fuse (in place over t_pad)
  tail_copy<<<T_TOK, 64, 0, stream>>>(xa_u, xg_pad + HID, 4160);
  gemm256<1><<<16 * 43, 512, LDS_BYTES, stream>>>(
      xg_pad, wB, t_pad, t_pad, nullptr, 43, 4160, 65, 11072);

  // down operand build (wA region is free after gate GEMM)
  cvt_pad<<<T_TOK, 256, 0, stream>>>(down_w, wA, 1376, IMD, 11072);
  build_wbT_pad<<<dim3(16, 64), 256, 0, stream>>>(down_wb, wA, HID, 11072, IMD);
  lora_proj<IMD, 1><<<T_TOK, 256, 0, stream>>>(
      t_pad, 11072, down_wa, nullptr, seg, t_pad + IMD, 11072, nullptr, 64);

  // down: out = t @ down_w^T + lora          [M=4096, N=4096, K'=11072]
  gemm256<2><<<16 * 16, 512, LDS_BYTES, stream>>>(
      t_pad, wA, nullptr, nullptr, (float*)d_out, 16, 11072, 173, 4096);
}